// Round 2
// baseline (192.989 us; speedup 1.0000x reference)
//
#include <hip/hip_runtime.h>
#include <hip/hip_bf16.h>

// Problem constants (fixed by the reference's setup_inputs)
#define C_DIM 64
#define P_DIM 16
#define K1V 3
#define K_DIM 9            // K1*K1
#define PK (P_DIM * K_DIM) // 144
// 1/(2*sqrt(2))
#define INV2S 0.35355339059327373f

// ---------------------------------------------------------------------------
// Kernel 1: out[n*16+p] = bias[p]   (d_out is poisoned each call)
// ---------------------------------------------------------------------------
__global__ __launch_bounds__(256) void init_out_kernel(float* __restrict__ out,
                                                       const float* __restrict__ bias,
                                                       int total) {
    int i = blockIdx.x * 256 + threadIdx.x;
    if (i < total) out[i] = bias[i & (P_DIM - 1)];
}

// ---------------------------------------------------------------------------
// Kernel 2: Z[n, p, k] = sum_c x[n,c] * W[p,k,c]   (N x 144 GEMM, K=64)
// Block: 256 threads, 64 rows of x per block.
// ---------------------------------------------------------------------------
__global__ __launch_bounds__(256) void z_gemm_kernel(const float* __restrict__ x,
                                                     const float* __restrict__ W,
                                                     float* __restrict__ Z,
                                                     int N) {
    __shared__ float Ws[C_DIM][PK + 1];    // [c][j], j = p*9+k   (37120 B)
    __shared__ float xs[C_DIM][C_DIM + 1]; // [c][row]            (16640 B)

    const int block_row = blockIdx.x * 64;

    // Stage W transposed: W[j*64 + c] -> Ws[c][j]
    for (int i = threadIdx.x; i < PK * C_DIM; i += 256) {
        int j = i >> 6, c = i & 63;
        Ws[c][j] = W[i];
    }
    // Stage x tile transposed: x[(block_row+r)*64 + c] -> xs[c][r]
    for (int i = threadIdx.x; i < C_DIM * C_DIM; i += 256) {
        int r = i >> 6, c = i & 63;
        int gr = block_row + r;
        xs[c][r] = (gr < N) ? x[(size_t)gr * C_DIM + c] : 0.0f;
    }
    __syncthreads();

    const int rg = threadIdx.x & 15;  // row group: rows rg*4 .. rg*4+3
    const int p  = threadIdx.x >> 4;  // 0..15

    float acc[4][K_DIM];
    #pragma unroll
    for (int i = 0; i < 4; ++i)
        #pragma unroll
        for (int k = 0; k < K_DIM; ++k) acc[i][k] = 0.0f;

    #pragma unroll 4
    for (int c = 0; c < C_DIM; ++c) {
        float xv[4];
        #pragma unroll
        for (int i = 0; i < 4; ++i) xv[i] = xs[c][rg * 4 + i];
        float wv[K_DIM];
        #pragma unroll
        for (int k = 0; k < K_DIM; ++k) wv[k] = Ws[c][p * K_DIM + k];
        #pragma unroll
        for (int i = 0; i < 4; ++i)
            #pragma unroll
            for (int k = 0; k < K_DIM; ++k)
                acc[i][k] = fmaf(xv[i], wv[k], acc[i][k]);
    }

    #pragma unroll
    for (int i = 0; i < 4; ++i) {
        int gr = block_row + rg * 4 + i;
        if (gr < N) {
            float* zp = Z + (size_t)gr * PK + p * K_DIM;
            #pragma unroll
            for (int k = 0; k < K_DIM; ++k) zp[k] = acc[i][k];
        }
    }
}

// ---------------------------------------------------------------------------
// Kernel 3: per (edge, p) message + scatter-add.
// thread -> (e = tid>>4, p = tid&15); 16 lanes share one edge.
// edge_index arrives as int32 [2][E] (harness converts integer inputs).
// ---------------------------------------------------------------------------
__global__ __launch_bounds__(256) void edge_kernel(const int* __restrict__ ei,
                                                   const float* __restrict__ pos,
                                                   const float* __restrict__ pose,
                                                   const float* __restrict__ Z,
                                                   float* __restrict__ out,
                                                   int E) {
    long long tid = (long long)blockIdx.x * 256 + threadIdx.x;
    if (tid >= (long long)E * P_DIM) return;
    const int e = (int)(tid >> 4);
    const int p = (int)(tid & 15);

    const int r = ei[e];       // row
    const int c = ei[E + e];   // col

    // d = pseudo - 0.5 = (pos[col]-pos[row]) / (2*sqrt(2))
    const float d0 = (pos[2 * c]     - pos[2 * r])     * INV2S;
    const float d1 = (pos[2 * c + 1] - pos[2 * r + 1]) * INV2S;

    const float2 ab = ((const float2*)pose)[(size_t)r * P_DIM + p];
    // rotated coord (rotation preserves |d| <= 0.354 so p in [0,1])
    const float p0 = fmaf(ab.x, d0, fmaf(-ab.y, d1, 0.5f));
    const float p1 = fmaf(ab.y, d0, fmaf( ab.x, d1, 0.5f));

    const float v0 = fminf(fmaxf(p0, 0.0f), 1.0f) * 2.0f;
    const float v1 = fminf(fmaxf(p1, 0.0f), 1.0f) * 2.0f;
    const float lo0 = floorf(v0);
    const float lo1 = floorf(v1);
    const float f0 = v0 - lo0;
    const float f1 = v1 - lo1;
    const int i00 = min((int)lo0, 2);        // lo >= 0 always
    const int i01 = min((int)lo0 + 1, 2);
    const int i10 = min((int)lo1, 2);
    const int i11 = min((int)lo1 + 1, 2);

    const float* __restrict__ Zp = Z + (size_t)c * PK + p * K_DIM;
    const float w00 = (1.0f - f0) * (1.0f - f1);
    const float w01 = (1.0f - f0) * f1;
    const float w10 = f0 * (1.0f - f1);
    const float w11 = f0 * f1;

    float m = w00 * Zp[i00 + 3 * i10];
    m = fmaf(w01, Zp[i00 + 3 * i11], m);
    m = fmaf(w10, Zp[i01 + 3 * i10], m);
    m = fmaf(w11, Zp[i01 + 3 * i11], m);

    atomicAdd(&out[(size_t)r * P_DIM + p], m);
}

// ---------------------------------------------------------------------------
extern "C" void kernel_launch(void* const* d_in, const int* in_sizes, int n_in,
                              void* d_out, int out_size, void* d_ws, size_t ws_size,
                              hipStream_t stream) {
    const float* x    = (const float*)d_in[0];
    const float* pos  = (const float*)d_in[1];
    const float* pose = (const float*)d_in[2];
    const float* W    = (const float*)d_in[3];
    const float* bias = (const float*)d_in[4];
    const int*   ei   = (const int*)d_in[5];   // int32 on device

    const int N = in_sizes[0] / C_DIM;   // 50000
    const int E = in_sizes[5] / 2;       // 800000

    float* Z   = (float*)d_ws;           // N * 144 floats = 28.8 MB
    float* out = (float*)d_out;          // N * 16 floats

    // out = bias broadcast
    init_out_kernel<<<(N * P_DIM + 255) / 256, 256, 0, stream>>>(out, bias, N * P_DIM);

    // Z = x @ W^T  (per p,k)
    z_gemm_kernel<<<(N + 63) / 64, 256, 0, stream>>>(x, W, Z, N);

    // edge messages + scatter-add
    const long long total = (long long)E * P_DIM;
    edge_kernel<<<(int)((total + 255) / 256), 256, 0, stream>>>(ei, pos, pose, Z, out, E);
}